// Round 1
// baseline (12062.939 us; speedup 1.0000x reference)
//
#include <hip/hip_runtime.h>

typedef _Float16 f16;
typedef _Float16 f16x8 __attribute__((ext_vector_type(8)));
typedef float f32x4 __attribute__((ext_vector_type(4)));

__device__ __forceinline__ f32x4 mfma16(f16x8 a, f16x8 b, f32x4 c) {
  return __builtin_amdgcn_mfma_f32_16x16x32_f16(a, b, c, 0, 0, 0);
}
__device__ __forceinline__ float sigm(float x) { return 1.0f / (1.0f + __expf(-x)); }
__device__ __forceinline__ float tanh_fast(float x) { return 1.0f - 2.0f / (__expf(2.0f * x) + 1.0f); }

// ---------------- workspace layout (bytes) ----------------
constexpr int NSTEPS = 128, BATCH = 256, HID = 512, G3 = 1536;
constexpr size_t SZ_WHH   = (size_t)G3 * HID * 2;            // 1.5 MB (f16)
constexpr size_t SZ_WLIN  = (size_t)HID * HID * 2;           // 0.5 MB
constexpr size_t SZ_WIH0P = (size_t)G3 * 8 * 2;              // 24 KB
constexpr size_t SZ_XPAD  = (size_t)NSTEPS * BATCH * 8 * 2;  // 0.5 MB
constexpr size_t SZ_Y     = (size_t)NSTEPS * BATCH * HID * 2;// 33.5 MB (y0 / y1 aliased)
constexpr size_t SZ_GI    = (size_t)NSTEPS * BATCH * G3 * 2; // 96 MB (f16)
constexpr size_t SZ_U     = (size_t)NSTEPS * BATCH * HID * 4;// 64 MB (f32)

constexpr size_t OFF_WHH0  = 0;
constexpr size_t OFF_WHH1  = OFF_WHH0 + SZ_WHH;
constexpr size_t OFF_WIH1  = OFF_WHH1 + SZ_WHH;
constexpr size_t OFF_WLIN  = OFF_WIH1 + SZ_WHH;
constexpr size_t OFF_WIH0P = OFF_WLIN + SZ_WLIN;
constexpr size_t OFF_XPAD  = OFF_WIH0P + SZ_WIH0P;
constexpr size_t OFF_Y     = OFF_XPAD + SZ_XPAD;
constexpr size_t OFF_GIU   = OFF_Y + SZ_Y;                   // gi1 (f16) then reused as u (f32)
constexpr size_t OFF_DIAG  = OFF_GIU + (SZ_GI > SZ_U ? SZ_GI : SZ_U);
// diag arrays: dsuf[32768] f32, de[32768] f32, du[32768*4] f32

// ---------------- prep: weight conversion + x packing ----------------
__global__ __launch_bounds__(256) void prep_k(
    const float* __restrict__ Whh0, const float* __restrict__ Whh1,
    const float* __restrict__ Wih1, const float* __restrict__ Wlin,
    const float* __restrict__ Wih0, const float* __restrict__ pn, const float* __restrict__ mn,
    f16* __restrict__ WHH0, f16* __restrict__ WHH1, f16* __restrict__ WIH1,
    f16* __restrict__ WLIN, f16* __restrict__ WIH0P, f16* __restrict__ XPAD)
{
  size_t i = (size_t)blockIdx.x * 256 + threadIdx.x;
  if (i < 786432)        { WHH0[i] = (f16)Whh0[i]; }
  else if (i < 1572864)  { size_t q = i - 786432;  WHH1[q] = (f16)Whh1[q]; }
  else if (i < 2359296)  { size_t q = i - 1572864; WIH1[q] = (f16)Wih1[q]; }
  else if (i < 2621440)  { size_t q = i - 2359296; WLIN[q] = (f16)Wlin[q]; }
  else if (i < 2633728)  { size_t q = i - 2621440; int n = (int)(q >> 3), c = (int)(q & 7);
                           WIH0P[q] = (c < 6) ? (f16)Wih0[n * 6 + c] : (f16)0.f; }
  else if (i < 2895872)  { size_t q = i - 2633728; size_t tb = q >> 3; int c = (int)(q & 7);
                           float v = (c < 4) ? pn[tb * 4 + c] : ((c < 6) ? mn[tb * 2 + (c - 4)] : 0.f);
                           XPAD[q] = (f16)v; }
}

// ---------------- GRU layer (persistent per batch-group, no inter-WG sync) ----------------
// 16 WGs x 512 threads (8 waves). WG g owns batch rows [16g, 16g+16).
// Wave w owns hidden cols [64w, 64w+64) = 4 j-tiles; gates r/z/n for those cols.
template<int LAYER>
__global__ __launch_bounds__(512, 1) void gru_layer_k(
    const f16* __restrict__ Whh,   // [1536][512]
    const f16* __restrict__ WihP,  // layer0: [1536][8]
    const f16* __restrict__ xpad,  // layer0: [t][256][8]
    const f16* __restrict__ gi,    // layer1: [t*256+b][1536] (b_ih1 already added)
    const float* __restrict__ hidden_in, // [2][256][512]
    const float* __restrict__ b_ih, const float* __restrict__ b_hh,
    f16* __restrict__ yout,        // [t*256+b][512]
    float* __restrict__ hT_out)    // [256][512] slice of d_out
{
  __shared__ float hF32[16][521];
  __shared__ __align__(16) f16 hF16[16 * 512];  // XOR-swizzled: byte = r*1024 + ((2j) ^ ((r&7)<<4))
  const int tid = threadIdx.x, lane = tid & 63, wid = tid >> 6;
  const int b0 = blockIdx.x * 16;
  const int colL = lane & 15, kgrp = lane >> 4;

  for (int e = tid; e < 16 * 512; e += 512) {
    int r = e >> 9, j = e & 511;
    float hv = hidden_in[((size_t)LAYER * 256 + b0 + r) * 512 + j];
    hF32[r][j] = hv;
    int sw = (((j >> 3) ^ (r & 7)) << 3) | (j & 7);
    hF16[r * 512 + sw] = (f16)hv;
  }

  float bs_r[4], bs_z[4], b_hn[4], b_in[4];
#pragma unroll
  for (int jt = 0; jt < 4; ++jt) {
    int j = wid * 64 + jt * 16 + colL;
    if constexpr (LAYER == 0) {
      bs_r[jt] = b_ih[j] + b_hh[j];
      bs_z[jt] = b_ih[512 + j] + b_hh[512 + j];
      b_in[jt] = b_ih[1024 + j];
    } else {
      bs_r[jt] = b_hh[j];
      bs_z[jt] = b_hh[512 + j];
      b_in[jt] = 0.f;
    }
    b_hn[jt] = b_hh[1024 + j];
  }
  __syncthreads();
  const char* hbytes = (const char*)hF16;

  for (int t = 0; t < 128; ++t) {
    // ---- per-step prefetch (consumed late; hidden under MFMA) ----
    f16x8 xA;
    float gr[4][4], gz[4][4], gn[4][4];
    if constexpr (LAYER == 0) {
#pragma unroll
      for (int q = 0; q < 8; ++q) xA[q] = (f16)0.f;
      if (kgrp == 0)
        xA = *(const f16x8*)(xpad + ((size_t)t * 256 + b0 + colL) * 8);
    } else {
      const f16* gibase = gi + ((size_t)t * 256 + b0 + kgrp * 4) * 1536;
#pragma unroll
      for (int i = 0; i < 4; ++i) {
        const f16* p = gibase + (size_t)i * 1536;
#pragma unroll
        for (int jt = 0; jt < 4; ++jt) {
          int j = wid * 64 + jt * 16 + colL;
          gr[jt][i] = (float)p[j];
          gz[jt][i] = (float)p[512 + j];
          gn[jt][i] = (float)p[1024 + j];
        }
      }
    }

    f32x4 acc_r[4], acc_z[4], acc_hn[4], acc_in[4];
#pragma unroll
    for (int jt = 0; jt < 4; ++jt)
#pragma unroll
      for (int q = 0; q < 4; ++q) {
        acc_r[jt][q] = 0.f; acc_z[jt][q] = 0.f; acc_hn[jt][q] = 0.f; acc_in[jt][q] = 0.f;
      }

    // ---- gh = h @ Whh^T   (K = 512 = 16 k-tiles) ----
#pragma unroll 2
    for (int kt = 0; kt < 16; ++kt) {
      f16x8 aF = *(const f16x8*)(hbytes + colL * 1024 + ((kt * 64 + kgrp * 16) ^ ((colL & 7) << 4)));
#pragma unroll
      for (int jt = 0; jt < 4; ++jt) {
        int jcol = wid * 64 + jt * 16 + colL;
        const f16* bb = Whh + (size_t)jcol * 512 + kt * 32 + kgrp * 8;
        f16x8 bR = *(const f16x8*)(bb);
        f16x8 bZ = *(const f16x8*)(bb + (size_t)512 * 512);
        f16x8 bN = *(const f16x8*)(bb + (size_t)1024 * 512);
        acc_r[jt]  = mfma16(aF, bR, acc_r[jt]);
        acc_z[jt]  = mfma16(aF, bZ, acc_z[jt]);
        acc_hn[jt] = mfma16(aF, bN, acc_hn[jt]);
      }
    }
    // ---- layer0: i-gates via one mostly-zero k-tile (K=6 padded to 8 real lanes) ----
    if constexpr (LAYER == 0) {
#pragma unroll
      for (int jt = 0; jt < 4; ++jt) {
        int jcol = wid * 64 + jt * 16 + colL;
        f16x8 bR, bZ, bN;
#pragma unroll
        for (int q = 0; q < 8; ++q) { bR[q] = (f16)0.f; bZ[q] = (f16)0.f; bN[q] = (f16)0.f; }
        if (kgrp == 0) {
          bR = *(const f16x8*)(WihP + (size_t)jcol * 8);
          bZ = *(const f16x8*)(WihP + (size_t)(512 + jcol) * 8);
          bN = *(const f16x8*)(WihP + (size_t)(1024 + jcol) * 8);
        }
        acc_r[jt]  = mfma16(xA, bR, acc_r[jt]);
        acc_z[jt]  = mfma16(xA, bZ, acc_z[jt]);
        acc_in[jt] = mfma16(xA, bN, acc_in[jt]);
      }
    }

    __syncthreads();  // all waves done reading hF16 of step t

    // ---- gate math + h update (each lane owns its (b, j) cells) ----
#pragma unroll
    for (int jt = 0; jt < 4; ++jt) {
      int j = wid * 64 + jt * 16 + colL;
#pragma unroll
      for (int i = 0; i < 4; ++i) {
        int b = kgrp * 4 + i;
        float rr, zz, hn, nin;
        if constexpr (LAYER == 0) {
          rr  = acc_r[jt][i] + bs_r[jt];
          zz  = acc_z[jt][i] + bs_z[jt];
          hn  = acc_hn[jt][i] + b_hn[jt];
          nin = acc_in[jt][i] + b_in[jt];
        } else {
          rr  = acc_r[jt][i] + gr[jt][i] + bs_r[jt];
          zz  = acc_z[jt][i] + gz[jt][i] + bs_z[jt];
          hn  = acc_hn[jt][i] + b_hn[jt];
          nin = gn[jt][i];
        }
        float r = sigm(rr), z = sigm(zz);
        float n = tanh_fast(nin + r * hn);
        float ho = hF32[b][j];
        float hnew = (1.f - z) * n + z * ho;
        hF32[b][j] = hnew;
        *(f16*)((char*)hF16 + b * 1024 + (((j << 1) ^ ((b & 7) << 4)))) = (f16)hnew;
      }
    }
    __syncthreads();  // hF16/hF32 of step t complete

    // ---- coalesced y store from LDS ----
    {
      const size_t rowbase = (size_t)t * 256 + b0;
#pragma unroll
      for (int c = 0; c < 2; ++c) {
        int id = c * 512 + tid;      // 1024 16B-chunks = 16 rows x 64 chunks
        int r = id >> 6, cb = id & 63;
        f16x8 v = *(const f16x8*)(hbytes + r * 1024 + ((cb * 16) ^ ((r & 7) << 4)));
        *(f16x8*)(yout + (rowbase + r) * 512 + cb * 8) = v;
      }
    }
  }

  __syncthreads();
  for (int e = tid; e < 16 * 512; e += 512) {
    int r = e >> 9, j = e & 511;
    hT_out[((size_t)b0 + r) * 512 + j] = hF32[r][j];
  }
}

// ---------------- gi1 = y0 @ Wih1^T + b_ih1  (M=32768, N=1536, K=512) ----------------
__global__ __launch_bounds__(256, 1) void gemm_gi1_k(
    const f16* __restrict__ A, const f16* __restrict__ B,
    const float* __restrict__ bias, f16* __restrict__ C)
{
  const int lane = threadIdx.x & 63, wid = threadIdx.x >> 6;
  const int colL = lane & 15, kgrp = lane >> 4;
  const int m0 = blockIdx.x * 64;
  const int n0 = blockIdx.y * 384 + wid * 96;
  f32x4 acc[4][6];
#pragma unroll
  for (int a = 0; a < 4; ++a)
#pragma unroll
    for (int n = 0; n < 6; ++n)
#pragma unroll
      for (int q = 0; q < 4; ++q) acc[a][n][q] = 0.f;

  for (int kt = 0; kt < 16; ++kt) {
    f16x8 aF[4];
#pragma unroll
    for (int at = 0; at < 4; ++at)
      aF[at] = *(const f16x8*)(A + ((size_t)(m0 + at * 16 + colL)) * 512 + kt * 32 + kgrp * 8);
#pragma unroll
    for (int nt = 0; nt < 6; ++nt) {
      f16x8 bF = *(const f16x8*)(B + ((size_t)(n0 + nt * 16 + colL)) * 512 + kt * 32 + kgrp * 8);
#pragma unroll
      for (int at = 0; at < 4; ++at)
        acc[at][nt] = mfma16(aF[at], bF, acc[at][nt]);
    }
  }
#pragma unroll
  for (int nt = 0; nt < 6; ++nt) {
    int col = n0 + nt * 16 + colL;
    float bv = bias[col];
#pragma unroll
    for (int at = 0; at < 4; ++at)
#pragma unroll
      for (int i = 0; i < 4; ++i)
        C[((size_t)(m0 + at * 16 + kgrp * 4 + i)) * 1536 + col] = (f16)(acc[at][nt][i] + bv);
  }
}

// ---------------- u = y1 @ Wlin^T + b_lin  (M=32768, N=512, K=512), fp32 out ----------------
__global__ __launch_bounds__(256, 1) void gemm_u_k(
    const f16* __restrict__ A, const f16* __restrict__ B,
    const float* __restrict__ bias, float* __restrict__ C)
{
  const int lane = threadIdx.x & 63, wid = threadIdx.x >> 6;
  const int colL = lane & 15, kgrp = lane >> 4;
  const int m0 = blockIdx.x * 64;
  const int n0 = wid * 128;
  f32x4 acc[4][8];
#pragma unroll
  for (int a = 0; a < 4; ++a)
#pragma unroll
    for (int n = 0; n < 8; ++n)
#pragma unroll
      for (int q = 0; q < 4; ++q) acc[a][n][q] = 0.f;

  for (int kt = 0; kt < 16; ++kt) {
    f16x8 aF[4];
#pragma unroll
    for (int at = 0; at < 4; ++at)
      aF[at] = *(const f16x8*)(A + ((size_t)(m0 + at * 16 + colL)) * 512 + kt * 32 + kgrp * 8);
#pragma unroll
    for (int nt = 0; nt < 8; ++nt) {
      f16x8 bF = *(const f16x8*)(B + ((size_t)(n0 + nt * 16 + colL)) * 512 + kt * 32 + kgrp * 8);
#pragma unroll
      for (int at = 0; at < 4; ++at)
        acc[at][nt] = mfma16(aF[at], bF, acc[at][nt]);
    }
  }
#pragma unroll
  for (int nt = 0; nt < 8; ++nt) {
    int col = n0 + nt * 16 + colL;
    float bv = bias[col];
#pragma unroll
    for (int at = 0; at < 4; ++at)
#pragma unroll
      for (int i = 0; i < 4; ++i)
        C[((size_t)(m0 + at * 16 + kgrp * 4 + i)) * 512 + col] = acc[at][nt][i] + bv;
  }
}

// ---------------- normalization pass 1: per (k,b) suffix energy + diag extract ----------------
__global__ __launch_bounds__(256) void norm1_k(const float* __restrict__ U,
    float* __restrict__ dsuf, float* __restrict__ de, float* __restrict__ du)
{
  int id = blockIdx.x * 4 + (threadIdx.x >> 6);  // row = k*256 + b in [0, 32768)
  int lane = threadIdx.x & 63;
  int k = id >> 8;
  const float* row = U + (size_t)id * 512;
  f32x4 v0 = *(const f32x4*)(row + lane * 8);
  f32x4 v1 = *(const f32x4*)(row + lane * 8 + 4);
  float vals[8] = {v0[0], v0[1], v0[2], v0[3], v1[0], v1[1], v1[2], v1[3]};
  int j0 = lane * 8;
  float s = 0.f;
#pragma unroll
  for (int q = 0; q < 8; ++q) {
    float v = ((j0 + q) >= 4 * k) ? vals[q] : 0.f;
    s += v * v;
  }
#pragma unroll
  for (int off = 1; off < 64; off <<= 1) s += __shfl_xor(s, off);
  if (lane == (k >> 1)) {
    int o = (k & 1) * 4;
    float e = vals[o] * vals[o] + vals[o + 1] * vals[o + 1] +
              vals[o + 2] * vals[o + 2] + vals[o + 3] * vals[o + 3];
    de[id] = e; dsuf[id] = s;
    f32x4 d = {vals[o], vals[o + 1], vals[o + 2], vals[o + 3]};
    *(f32x4*)(du + (size_t)id * 4) = d;
  }
}

// ---------------- normalization pass 2: cumprod over k, write u_N ----------------
__global__ __launch_bounds__(256) void norm2_k(const float* __restrict__ dsuf,
    const float* __restrict__ de, const float* __restrict__ du, float* __restrict__ out)
{
  int b = threadIdx.x;
  float L = 128.f;
  for (int kc = 0; kc < 8; ++kc) {
    float ss[16], ee[16]; f32x4 dd[16];
#pragma unroll
    for (int q = 0; q < 16; ++q) {
      int id = (kc * 16 + q) * 256 + b;
      ss[q] = dsuf[id]; ee[q] = de[id];
      dd[q] = *(const f32x4*)(du + (size_t)id * 4);
    }
#pragma unroll
    for (int q = 0; q < 16; ++q) {
      int id = (kc * 16 + q) * 256 + b;
      float sc = sqrtf(L / ss[q]);
      f32x4 o = dd[q];
      o[0] *= sc; o[1] *= sc; o[2] *= sc; o[3] *= sc;
      *(f32x4*)(out + (size_t)id * 4) = o;
      L *= (1.f - ee[q] / ss[q]);
    }
  }
}

// ---------------- launch ----------------
extern "C" void kernel_launch(void* const* d_in, const int* in_sizes, int n_in,
                              void* d_out, int out_size, void* d_ws, size_t ws_size,
                              hipStream_t stream) {
  (void)in_sizes; (void)n_in; (void)out_size; (void)ws_size;
  const float* pn   = (const float*)d_in[0];
  const float* mn   = (const float*)d_in[1];
  const float* hid  = (const float*)d_in[2];
  const float* Wih0 = (const float*)d_in[3];
  const float* Whh0 = (const float*)d_in[4];
  const float* bih0 = (const float*)d_in[5];
  const float* bhh0 = (const float*)d_in[6];
  const float* Wih1 = (const float*)d_in[7];
  const float* Whh1 = (const float*)d_in[8];
  const float* bih1 = (const float*)d_in[9];
  const float* bhh1 = (const float*)d_in[10];
  const float* Wlin = (const float*)d_in[11];
  const float* blin = (const float*)d_in[12];
  float* out = (float*)d_out;
  char* ws = (char*)d_ws;

  f16* WHH0  = (f16*)(ws + OFF_WHH0);
  f16* WHH1  = (f16*)(ws + OFF_WHH1);
  f16* WIH1  = (f16*)(ws + OFF_WIH1);
  f16* WLIN  = (f16*)(ws + OFF_WLIN);
  f16* WIH0P = (f16*)(ws + OFF_WIH0P);
  f16* XPAD  = (f16*)(ws + OFF_XPAD);
  f16* Y     = (f16*)(ws + OFF_Y);
  f16* GI1   = (f16*)(ws + OFF_GIU);
  float* U   = (float*)(ws + OFF_GIU);
  float* DSUF = (float*)(ws + OFF_DIAG);
  float* DE   = (float*)(ws + OFF_DIAG + 131072);
  float* DU   = (float*)(ws + OFF_DIAG + 262144);

  prep_k<<<11312, 256, 0, stream>>>(Whh0, Whh1, Wih1, Wlin, Wih0, pn, mn,
                                    WHH0, WHH1, WIH1, WLIN, WIH0P, XPAD);
  gru_layer_k<0><<<16, 512, 0, stream>>>(WHH0, WIH0P, XPAD, nullptr, hid, bih0, bhh0,
                                         Y, out + 131072);
  gemm_gi1_k<<<dim3(512, 4), 256, 0, stream>>>(Y, WIH1, bih1, GI1);
  gru_layer_k<1><<<16, 512, 0, stream>>>(WHH1, nullptr, nullptr, GI1, hid, bih1, bhh1,
                                         Y, out + 262144);
  gemm_u_k<<<512, 256, 0, stream>>>(Y, WLIN, blin, U);
  norm1_k<<<8192, 256, 0, stream>>>(U, DSUF, DE, DU);
  norm2_k<<<1, 256, 0, stream>>>(DSUF, DE, DU, out);
}

// Round 3
// 4838.508 us; speedup vs baseline: 2.4931x; 2.4931x over previous
//
#include <hip/hip_runtime.h>

typedef _Float16 f16;
typedef _Float16 f16x8 __attribute__((ext_vector_type(8)));
typedef _Float16 f16x4 __attribute__((ext_vector_type(4)));
typedef float f32x4 __attribute__((ext_vector_type(4)));

__device__ __forceinline__ f32x4 mfma16(f16x8 a, f16x8 b, f32x4 c) {
  return __builtin_amdgcn_mfma_f32_16x16x32_f16(a, b, c, 0, 0, 0);
}
__device__ __forceinline__ float sigm(float x) { return 1.0f / (1.0f + __expf(-x)); }
__device__ __forceinline__ float tanh_fast(float x) { return 1.0f - 2.0f / (__expf(2.0f * x) + 1.0f); }

// ---------------- workspace layout (bytes) ----------------
constexpr size_t OFF_WHH0P = 0;                       // packed Whh L0, 1.5MB
constexpr size_t OFF_WHH1P = 1572864;                 // packed Whh L1, 1.5MB
constexpr size_t OFF_WIH1  = 3145728;                 // plain f16 [1536][512], 1.5MB
constexpr size_t OFF_WLIN  = 4718592;                 // plain f16 [512][512], 0.5MB
constexpr size_t OFF_WP0   = 5242880;                 // layer0 Wih frags, 96KB
constexpr size_t OFF_XPAD  = 5341184;                 // [128][256][8] f16, 512KB
constexpr size_t OFF_Y     = 5865472;                 // [32768][512] f16, 32MB
constexpr size_t OFF_GIU   = 39419904;                // GIP f16 (100.7MB) then U f32 (64MB)
constexpr size_t OFF_DIAG  = 140083200;               // dsuf/de/du

// ---------------- prep: pack Whh into MFMA-fragment order ----------------
// PW layout: [kt(16)][wid(8)][r(12)][lane(64)][8 f16]; r = g*4+jt
// content: row = g*512 + wid*64 + jt*16 + (lane&15); k = kt*32 + (lane>>4)*8
__global__ __launch_bounds__(256) void prep_pack_k(
    const float* __restrict__ Whh0, const float* __restrict__ Whh1,
    f16* __restrict__ P0, f16* __restrict__ P1)
{
  int idx = blockIdx.x * 256 + threadIdx.x;          // 0..196607
  const float* W = (idx < 98304) ? Whh0 : Whh1;
  f16* P = (idx < 98304) ? P0 : P1;
  // NOTE: 98304 = 3*2^15 is NOT a power of two -> must subtract, not mask.
  int q = (idx < 98304) ? idx : idx - 98304;
  int lane = q & 63; int u = q >> 6;
  int r = u % 12; int v = u / 12; int wd = v & 7; int kt = v >> 3;
  int row = (r >> 2) * 512 + wd * 64 + (r & 3) * 16 + (lane & 15);
  int k = kt * 32 + (lane >> 4) * 8;
  const float* src = W + (size_t)row * 512 + k;
  f16* dst = P + (size_t)q * 8;
#pragma unroll
  for (int c = 0; c < 8; ++c) dst[c] = (f16)src[c];
}

// ---------------- prep: everything else ----------------
__global__ __launch_bounds__(256) void prep_misc_k(
    const float* __restrict__ Wih1, const float* __restrict__ Wlin,
    const float* __restrict__ Wih0, const float* __restrict__ pn, const float* __restrict__ mn,
    f16* __restrict__ WIH1, f16* __restrict__ WLIN, f16* __restrict__ WP0, f16* __restrict__ XPAD)
{
  int i = blockIdx.x * 256 + threadIdx.x;            // 0..1087487
  if (i < 786432) { WIH1[i] = (f16)Wih1[i]; return; }
  i -= 786432;
  if (i < 262144) { WLIN[i] = (f16)Wlin[i]; return; }
  i -= 262144;
  if (i < 6144) {                                     // WP0 groups: [wid][r][lane][8]
    int lane = i & 63; int u = i >> 6;
    int r = u % 12; int wd = u / 12;
    int colL = lane & 15, kg = lane >> 4;
    int row = (r >> 2) * 512 + wd * 64 + (r & 3) * 16 + colL;
    f16* dst = WP0 + (size_t)i * 8;
#pragma unroll
    for (int c = 0; c < 8; ++c)
      dst[c] = (kg == 0 && c < 6) ? (f16)Wih0[row * 6 + c] : (f16)0.f;
    return;
  }
  i -= 6144;
  {                                                   // XPAD groups: tb in [0,32768)
    size_t tb = i;
    f16* dst = XPAD + tb * 8;
#pragma unroll
    for (int c = 0; c < 8; ++c) {
      float v = (c < 4) ? pn[tb * 4 + c] : ((c < 6) ? mn[tb * 2 + (c - 4)] : 0.f);
      dst[c] = (f16)v;
    }
  }
}

// ---------------- GRU layer: 16 WGs x 512 thr, register h, 16-deep B ring ----------------
template<int LAYER>
__global__ __launch_bounds__(512) void gru2_k(
    const f16* __restrict__ PW,     // packed Whh
    const f16* __restrict__ WP0,    // layer0 input-weight frags
    const f16* __restrict__ xpad,   // layer0 [t][256][8]
    const f16* __restrict__ gip,    // layer1 packed gi
    const float* __restrict__ hidden_in,
    const float* __restrict__ b_ih, const float* __restrict__ b_hh,
    f16* __restrict__ yout, float* __restrict__ hT_out)
{
  __shared__ __align__(16) f16 hF16[8192];   // swizzled: byte = b*1024 + ((2j)^((b&7)<<4))
  const int tid = threadIdx.x, lane = tid & 63, wid = tid >> 6;
  const int b0 = blockIdx.x * 16;
  const int colL = lane & 15, kgrp = lane >> 4;

  for (int e = tid; e < 8192; e += 512) {
    int rr = e >> 9, j = e & 511;
    float hv = hidden_in[((size_t)LAYER * 256 + b0 + rr) * 512 + j];
    int sw = (((j >> 3) ^ (rr & 7)) << 3) | (j & 7);
    hF16[rr * 512 + sw] = (f16)hv;
  }

  float h[4][4];
#pragma unroll
  for (int jt = 0; jt < 4; ++jt)
#pragma unroll
    for (int i = 0; i < 4; ++i)
      h[jt][i] = hidden_in[((size_t)LAYER * 256 + b0 + kgrp * 4 + i) * 512 + wid * 64 + jt * 16 + colL];

  float bs_r[4], bs_z[4], b_hn[4], b_in[4];
#pragma unroll
  for (int jt = 0; jt < 4; ++jt) {
    int j = wid * 64 + jt * 16 + colL;
    if constexpr (LAYER == 0) {
      bs_r[jt] = b_ih[j] + b_hh[j];
      bs_z[jt] = b_ih[512 + j] + b_hh[512 + j];
      b_in[jt] = b_ih[1024 + j];
    } else {
      bs_r[jt] = b_hh[j];
      bs_z[jt] = b_hh[512 + j];
      b_in[jt] = 0.f;
    }
    b_hn[jt] = b_hh[1024 + j];
  }

  // layer0: persistent input-weight fragments (L1/regs), x fragment
  f16x8 WPreg[12];
  f16x8 xA;
#pragma unroll
  for (int q = 0; q < 8; ++q) xA[q] = (f16)0.f;
  if constexpr (LAYER == 0) {
#pragma unroll
    for (int rr = 0; rr < 12; ++rr)
      WPreg[rr] = *(const f16x8*)(WP0 + ((size_t)(wid * 12 + rr) * 64 + lane) * 8);
    if (kgrp == 0)
      xA = *(const f16x8*)(xpad + ((size_t)b0 + colL) * 8);
  }
  // layer1: gi fragments for t=0
  f16x4 giR[4], giZ[4], giN[4];
  if constexpr (LAYER == 1) {
    size_t blk = ((size_t)blockIdx.x * 8 + wid) * 12;
#pragma unroll
    for (int jt = 0; jt < 4; ++jt) {
      giR[jt] = *(const f16x4*)(gip + (blk + 0 + jt) * 256 + lane * 4);
      giZ[jt] = *(const f16x4*)(gip + (blk + 4 + jt) * 256 + lane * 4);
      giN[jt] = *(const f16x4*)(gip + (blk + 8 + jt) * 256 + lane * 4);
    }
  }

  __syncthreads();
  const char* hb = (const char*)hF16;

  // B-ring prologue: fragments 0..15 (continuous across steps; same weights every step)
  f16x8 B[16];
#pragma unroll
  for (int f = 0; f < 16; ++f) {
    int kt = f / 12, rr = f % 12;
    B[f] = *(const f16x8*)(PW + ((size_t)((kt * 8 + wid) * 12 + rr) * 512 + lane * 8));
  }

#pragma unroll 1
  for (int t = 0; t < 128; ++t) {
    f32x4 acc[3][4], acc_in[4];
#pragma unroll
    for (int g = 0; g < 3; ++g)
#pragma unroll
      for (int jt = 0; jt < 4; ++jt)
#pragma unroll
        for (int q = 0; q < 4; ++q) acc[g][jt][q] = 0.f;
#pragma unroll
    for (int jt = 0; jt < 4; ++jt)
#pragma unroll
      for (int q = 0; q < 4; ++q) acc_in[jt][q] = 0.f;

    f16x8 aF;
#pragma unroll 1
    for (int fb = 0; fb < 4; ++fb) {
#pragma unroll
      for (int p = 0; p < 48; ++p) {
        const int ktl = p / 12, rr = p % 12;
        const int g = rr >> 2, jt = rr & 3;
        if (rr == 0) {
          int kt = fb * 4 + ktl;
          aF = *(const f16x8*)(hb + colL * 1024 + ((kt * 64 + kgrp * 16) ^ ((colL & 7) << 4)));
        }
        acc[g][jt] = mfma16(aF, B[p & 15], acc[g][jt]);
        // stage fragment p+16 (wraps across kt and across steps: same weights)
        const int q2 = p + 16;
        int ktn = (fb * 4 + q2 / 12) & 15, rn = q2 % 12;
        B[p & 15] = *(const f16x8*)(PW + ((size_t)((ktn * 8 + wid) * 12 + rn) * 512 + lane * 8));
      }
    }

    if constexpr (LAYER == 0) {
#pragma unroll
      for (int jt = 0; jt < 4; ++jt) {
        acc[0][jt] = mfma16(xA, WPreg[jt], acc[0][jt]);
        acc[1][jt] = mfma16(xA, WPreg[4 + jt], acc[1][jt]);
        acc_in[jt] = mfma16(xA, WPreg[8 + jt], acc_in[jt]);
      }
    }

    __syncthreads();   // barrier 1: all waves done reading hF16(t)

    // gate math + h update (lane owns b=kgrp*4+i, j=wid*64+jt*16+colL)
#pragma unroll
    for (int jt = 0; jt < 4; ++jt) {
      int j = wid * 64 + jt * 16 + colL;
#pragma unroll
      for (int i = 0; i < 4; ++i) {
        float rr, zz, hn, nin;
        if constexpr (LAYER == 0) {
          rr  = acc[0][jt][i] + bs_r[jt];
          zz  = acc[1][jt][i] + bs_z[jt];
          hn  = acc[2][jt][i] + b_hn[jt];
          nin = acc_in[jt][i] + b_in[jt];
        } else {
          rr  = acc[0][jt][i] + (float)giR[jt][i] + bs_r[jt];
          zz  = acc[1][jt][i] + (float)giZ[jt][i] + bs_z[jt];
          hn  = acc[2][jt][i] + b_hn[jt];
          nin = (float)giN[jt][i];
        }
        float r = sigm(rr), z = sigm(zz);
        float n = tanh_fast(nin + r * hn);
        float hnew = (1.f - z) * n + z * h[jt][i];
        h[jt][i] = hnew;
        int b = kgrp * 4 + i;
        *(f16*)((char*)hF16 + b * 1024 + (((j << 1)) ^ ((b & 7) << 4))) = (f16)hnew;
      }
    }

    // issue next step's x / gi fragments (consumed after next barrier pair)
    {
      int tn = (t + 1) & 127;
      if constexpr (LAYER == 0) {
        if (kgrp == 0)
          xA = *(const f16x8*)(xpad + ((size_t)tn * 256 + b0 + colL) * 8);
      } else {
        size_t blk = (((size_t)tn * 16 + blockIdx.x) * 8 + wid) * 12;
#pragma unroll
        for (int jt = 0; jt < 4; ++jt) {
          giR[jt] = *(const f16x4*)(gip + (blk + 0 + jt) * 256 + lane * 4);
          giZ[jt] = *(const f16x4*)(gip + (blk + 4 + jt) * 256 + lane * 4);
          giN[jt] = *(const f16x4*)(gip + (blk + 8 + jt) * 256 + lane * 4);
        }
      }
    }

    __syncthreads();   // barrier 2: hF16(t+1) complete

    {  // coalesced y store from LDS
      const size_t rowbase = (size_t)t * 256 + b0;
#pragma unroll
      for (int c = 0; c < 2; ++c) {
        int id = c * 512 + tid;
        int rr = id >> 6, cb = id & 63;
        f16x8 v = *(const f16x8*)(hb + rr * 1024 + ((cb * 16) ^ ((rr & 7) << 4)));
        *(f16x8*)(yout + (rowbase + rr) * 512 + cb * 8) = v;
      }
    }
  }

#pragma unroll
  for (int jt = 0; jt < 4; ++jt)
#pragma unroll
    for (int i = 0; i < 4; ++i)
      hT_out[((size_t)b0 + kgrp * 4 + i) * 512 + wid * 64 + jt * 16 + colL] = h[jt][i];
}

// ---------------- gi1 = y0 @ Wih1^T + b_ih1, written in GRU fragment layout ----------------
__global__ __launch_bounds__(256, 1) void gemm_gi1_k(
    const f16* __restrict__ A, const f16* __restrict__ B,
    const float* __restrict__ bias, f16* __restrict__ GIP)
{
  const int lane = threadIdx.x & 63, wd = threadIdx.x >> 6;
  const int colL = lane & 15, kgrp = lane >> 4;
  const int m0 = blockIdx.x * 64;
  const int n0 = blockIdx.y * 384 + wd * 96;
  f32x4 acc[4][6];
#pragma unroll
  for (int a = 0; a < 4; ++a)
#pragma unroll
    for (int n = 0; n < 6; ++n)
#pragma unroll
      for (int q = 0; q < 4; ++q) acc[a][n][q] = 0.f;

  for (int kt = 0; kt < 16; ++kt) {
    f16x8 aF[4];
#pragma unroll
    for (int at = 0; at < 4; ++at)
      aF[at] = *(const f16x8*)(A + ((size_t)(m0 + at * 16 + colL)) * 512 + kt * 32 + kgrp * 8);
#pragma unroll
    for (int nt = 0; nt < 6; ++nt) {
      f16x8 bF = *(const f16x8*)(B + ((size_t)(n0 + nt * 16 + colL)) * 512 + kt * 32 + kgrp * 8);
#pragma unroll
      for (int at = 0; at < 4; ++at)
        acc[at][nt] = mfma16(aF[at], bF, acc[at][nt]);
    }
  }

  const int t = m0 >> 8;
  const int bgbase = (m0 & 255) >> 4;
#pragma unroll
  for (int nt = 0; nt < 6; ++nt) {
    int colbase = n0 + nt * 16;
    int g = colbase >> 9;
    int jb = colbase & 511;
    int wid2 = jb >> 6, jt = (jb >> 4) & 3;
    float bv = bias[colbase + colL];
#pragma unroll
    for (int at = 0; at < 4; ++at) {
      size_t blk = ((((size_t)t * 16 + bgbase + at) * 8 + wid2) * 12 + g * 4 + jt);
      f16x4 v = {(f16)(acc[at][nt][0] + bv), (f16)(acc[at][nt][1] + bv),
                 (f16)(acc[at][nt][2] + bv), (f16)(acc[at][nt][3] + bv)};
      *(f16x4*)(GIP + blk * 256 + lane * 4) = v;
    }
  }
}

// ---------------- u = y1 @ Wlin^T + b_lin (fp32 out) ----------------
__global__ __launch_bounds__(256, 1) void gemm_u_k(
    const f16* __restrict__ A, const f16* __restrict__ B,
    const float* __restrict__ bias, float* __restrict__ C)
{
  const int lane = threadIdx.x & 63, wd = threadIdx.x >> 6;
  const int colL = lane & 15, kgrp = lane >> 4;
  const int m0 = blockIdx.x * 64;
  const int n0 = wd * 128;
  f32x4 acc[4][8];
#pragma unroll
  for (int a = 0; a < 4; ++a)
#pragma unroll
    for (int n = 0; n < 8; ++n)
#pragma unroll
      for (int q = 0; q < 4; ++q) acc[a][n][q] = 0.f;

  for (int kt = 0; kt < 16; ++kt) {
    f16x8 aF[4];
#pragma unroll
    for (int at = 0; at < 4; ++at)
      aF[at] = *(const f16x8*)(A + ((size_t)(m0 + at * 16 + colL)) * 512 + kt * 32 + kgrp * 8);
#pragma unroll
    for (int nt = 0; nt < 8; ++nt) {
      f16x8 bF = *(const f16x8*)(B + ((size_t)(n0 + nt * 16 + colL)) * 512 + kt * 32 + kgrp * 8);
#pragma unroll
      for (int at = 0; at < 4; ++at)
        acc[at][nt] = mfma16(aF[at], bF, acc[at][nt]);
    }
  }
#pragma unroll
  for (int nt = 0; nt < 8; ++nt) {
    int col = n0 + nt * 16 + colL;
    float bv = bias[col];
#pragma unroll
    for (int at = 0; at < 4; ++at)
#pragma unroll
      for (int i = 0; i < 4; ++i)
        C[((size_t)(m0 + at * 16 + kgrp * 4 + i)) * 512 + col] = acc[at][nt][i] + bv;
  }
}

// ---------------- normalization pass 1 ----------------
__global__ __launch_bounds__(256) void norm1_k(const float* __restrict__ U,
    float* __restrict__ dsuf, float* __restrict__ de, float* __restrict__ du)
{
  int id = blockIdx.x * 4 + (threadIdx.x >> 6);
  int lane = threadIdx.x & 63;
  int k = id >> 8;
  const float* row = U + (size_t)id * 512;
  f32x4 v0 = *(const f32x4*)(row + lane * 8);
  f32x4 v1 = *(const f32x4*)(row + lane * 8 + 4);
  float vals[8] = {v0[0], v0[1], v0[2], v0[3], v1[0], v1[1], v1[2], v1[3]};
  int j0 = lane * 8;
  float s = 0.f;
#pragma unroll
  for (int q = 0; q < 8; ++q) {
    float v = ((j0 + q) >= 4 * k) ? vals[q] : 0.f;
    s += v * v;
  }
#pragma unroll
  for (int off = 1; off < 64; off <<= 1) s += __shfl_xor(s, off);
  if (lane == (k >> 1)) {
    int o = (k & 1) * 4;
    float e = vals[o] * vals[o] + vals[o + 1] * vals[o + 1] +
              vals[o + 2] * vals[o + 2] + vals[o + 3] * vals[o + 3];
    de[id] = e; dsuf[id] = s;
    f32x4 d = {vals[o], vals[o + 1], vals[o + 2], vals[o + 3]};
    *(f32x4*)(du + (size_t)id * 4) = d;
  }
}

// ---------------- normalization pass 2 ----------------
__global__ __launch_bounds__(256) void norm2_k(const float* __restrict__ dsuf,
    const float* __restrict__ de, const float* __restrict__ du, float* __restrict__ out)
{
  int b = threadIdx.x;
  float L = 128.f;
  for (int kc = 0; kc < 8; ++kc) {
    float ss[16], ee[16]; f32x4 dd[16];
#pragma unroll
    for (int q = 0; q < 16; ++q) {
      int id = (kc * 16 + q) * 256 + b;
      ss[q] = dsuf[id]; ee[q] = de[id];
      dd[q] = *(const f32x4*)(du + (size_t)id * 4);
    }
#pragma unroll
    for (int q = 0; q < 16; ++q) {
      int id = (kc * 16 + q) * 256 + b;
      float sc = sqrtf(L / ss[q]);
      f32x4 o = dd[q];
      o[0] *= sc; o[1] *= sc; o[2] *= sc; o[3] *= sc;
      *(f32x4*)(out + (size_t)id * 4) = o;
      L *= (1.f - ee[q] / ss[q]);
    }
  }
}

// ---------------- launch ----------------
extern "C" void kernel_launch(void* const* d_in, const int* in_sizes, int n_in,
                              void* d_out, int out_size, void* d_ws, size_t ws_size,
                              hipStream_t stream) {
  (void)in_sizes; (void)n_in; (void)out_size; (void)ws_size;
  const float* pn   = (const float*)d_in[0];
  const float* mn   = (const float*)d_in[1];
  const float* hid  = (const float*)d_in[2];
  const float* Wih0 = (const float*)d_in[3];
  const float* Whh0 = (const float*)d_in[4];
  const float* bih0 = (const float*)d_in[5];
  const float* bhh0 = (const float*)d_in[6];
  const float* Wih1 = (const float*)d_in[7];
  const float* Whh1 = (const float*)d_in[8];
  const float* bih1 = (const float*)d_in[9];
  const float* bhh1 = (const float*)d_in[10];
  const float* Wlin = (const float*)d_in[11];
  const float* blin = (const float*)d_in[12];
  float* out = (float*)d_out;
  char* ws = (char*)d_ws;

  f16* WHH0P = (f16*)(ws + OFF_WHH0P);
  f16* WHH1P = (f16*)(ws + OFF_WHH1P);
  f16* WIH1  = (f16*)(ws + OFF_WIH1);
  f16* WLIN  = (f16*)(ws + OFF_WLIN);
  f16* WP0   = (f16*)(ws + OFF_WP0);
  f16* XPAD  = (f16*)(ws + OFF_XPAD);
  f16* Y     = (f16*)(ws + OFF_Y);
  f16* GIP   = (f16*)(ws + OFF_GIU);
  float* U   = (float*)(ws + OFF_GIU);
  float* DSUF = (float*)(ws + OFF_DIAG);
  float* DE   = (float*)(ws + OFF_DIAG + 131072);
  float* DU   = (float*)(ws + OFF_DIAG + 262144);

  prep_pack_k<<<768, 256, 0, stream>>>(Whh0, Whh1, WHH0P, WHH1P);
  prep_misc_k<<<4248, 256, 0, stream>>>(Wih1, Wlin, Wih0, pn, mn, WIH1, WLIN, WP0, XPAD);
  gru2_k<0><<<16, 512, 0, stream>>>(WHH0P, WP0, XPAD, nullptr, hid, bih0, bhh0,
                                    Y, out + 131072);
  gemm_gi1_k<<<dim3(512, 4), 256, 0, stream>>>(Y, WIH1, bih1, GIP);
  gru2_k<1><<<16, 512, 0, stream>>>(WHH1P, nullptr, nullptr, GIP, hid, bih1, bhh1,
                                    Y, out + 262144);
  gemm_u_k<<<512, 256, 0, stream>>>(Y, WLIN, blin, U);
  norm1_k<<<8192, 256, 0, stream>>>(U, DSUF, DE, DU);
  norm2_k<<<1, 256, 0, stream>>>(DSUF, DE, DU, out);
}